// Round 20
// baseline (2052.088 us; speedup 1.0000x reference)
//
#include <hip/hip_runtime.h>
#include <hip/hip_bf16.h>

#define T_TOK 4096
#define HDIM  1024
#define NEXP  8
#define IDIM  1408
#define ISDIM 2816
#define PADT  10240   // 40 tiles of 256 (worst-case padded expert rows)

typedef short bf16x8 __attribute__((ext_vector_type(8)));
typedef float f32x4  __attribute__((ext_vector_type(4)));
typedef unsigned short u16;
typedef unsigned short u16x4 __attribute__((ext_vector_type(4)));
typedef unsigned short u16x8 __attribute__((ext_vector_type(8)));

typedef __attribute__((address_space(1))) const void gvoid;
typedef __attribute__((address_space(3))) void lvoid;

__device__ __forceinline__ u16 f2bf(float f) {
    union { float f; unsigned u; } c; c.f = f;
    unsigned r = (c.u + 0x7FFFu + ((c.u >> 16) & 1u)) >> 16;
    return (u16)r;
}
__device__ __forceinline__ float bf2f(u16 v) {
    union { unsigned u; float f; } c; c.u = (unsigned)v << 16; return c.f;
}
__device__ __forceinline__ void glds16(const u16* g, u16* l) {
    __builtin_amdgcn_global_load_lds((gvoid*)g, (lvoid*)l, 16, 0, 0);
}

// ---------------- routing: one wave per token (no atomics) + fused X->bf16 ----------------
__global__ __launch_bounds__(256) void route_kernel(
    const float* __restrict__ X, const float* __restrict__ GW,
    const float* __restrict__ SEG,
    int* __restrict__ topk_e, float* __restrict__ topk_w,
    float* __restrict__ sgate, u16* __restrict__ Xbf)
{
    const int t = blockIdx.x * 4 + (threadIdx.x >> 6);
    const int lane = threadIdx.x & 63;
    float acc[NEXP];
    #pragma unroll
    for (int e = 0; e < NEXP; ++e) acc[e] = 0.f;
    float sacc = 0.f;
    const float* xr = X + (size_t)t * HDIM;
    u16* xw = Xbf + (size_t)t * HDIM;
    for (int h = lane; h < HDIM; h += 64) {
        float xv = xr[h];
        xw[h] = f2bf(xv);
        f32x4 g0 = *(const f32x4*)(GW + (size_t)h * NEXP);
        f32x4 g1 = *(const f32x4*)(GW + (size_t)h * NEXP + 4);
        acc[0] += xv * g0[0]; acc[1] += xv * g0[1];
        acc[2] += xv * g0[2]; acc[3] += xv * g0[3];
        acc[4] += xv * g1[0]; acc[5] += xv * g1[1];
        acc[6] += xv * g1[2]; acc[7] += xv * g1[3];
        sacc += xv * SEG[h];
    }
    #pragma unroll
    for (int off = 32; off > 0; off >>= 1) {
        #pragma unroll
        for (int e = 0; e < NEXP; ++e) acc[e] += __shfl_down(acc[e], off);
        sacc += __shfl_down(sacc, off);
    }
    if (lane == 0) {
        int e0 = 0;
        #pragma unroll
        for (int e = 1; e < NEXP; ++e) if (acc[e] > acc[e0]) e0 = e;
        int e1 = (e0 == 0) ? 1 : 0;
        #pragma unroll
        for (int e = 0; e < NEXP; ++e)
            if (e != e0 && acc[e] > acc[e1]) e1 = e;
        float w0 = 1.f / (1.f + __expf(acc[e1] - acc[e0]));
        topk_e[t * 2]     = e0; topk_e[t * 2 + 1] = e1;
        topk_w[t * 2]     = w0; topk_w[t * 2 + 1] = 1.f - w0;
        sgate[t] = 1.f / (1.f + __expf(-sacc));
    }
}

// ---------------- histogram (+ tok_ids prefill) ----------------
__global__ __launch_bounds__(256) void hist_kernel(
    const int* __restrict__ topk_e, int* __restrict__ counts,
    int* __restrict__ tok_ids)
{
    __shared__ int h[NEXP];
    if (threadIdx.x < NEXP) h[threadIdx.x] = 0;
    __syncthreads();
    int i = blockIdx.x * 256 + threadIdx.x;
    atomicAdd(&h[topk_e[i]], 1);
    for (int j = i; j < PADT; j += gridDim.x * 256) tok_ids[j] = 0;
    __syncthreads();
    if (threadIdx.x < NEXP) atomicAdd(&counts[threadIdx.x], h[threadIdx.x]);
}

// seg_pad[e]: 256-aligned padded segment starts; seg_pad[8] = padded total
__global__ void offsets_kernel(const int* __restrict__ counts,
                               int* __restrict__ seg_pad,
                               int* __restrict__ cursors)
{
    if (threadIdx.x == 0) {
        int s = 0;
        for (int e = 0; e < NEXP; ++e) {
            seg_pad[e] = s; cursors[e] = s;
            s += ((counts[e] + 255) >> 8) << 8;
        }
        seg_pad[NEXP] = s;
    }
}

// ---------------- scatter (writes tok_ids + slot inverse map) ----------------
__global__ __launch_bounds__(256) void scatter_kernel(
    const int* __restrict__ topk_e,
    int* __restrict__ cursors, int* __restrict__ tok_ids,
    int* __restrict__ slot)
{
    const int i = blockIdx.x * 256 + threadIdx.x;
    const int lane = threadIdx.x & 63;
    const int e = topk_e[i];
    const unsigned long long lt = (1ull << lane) - 1ull;
    #pragma unroll
    for (int ex = 0; ex < NEXP; ++ex) {
        unsigned long long mask = __ballot(e == ex);
        if (mask == 0ull) continue;
        int cnt = __popcll(mask);
        int leader = __ffsll((long long)mask) - 1;
        int base_ = 0;
        if (lane == leader) base_ = atomicAdd(&cursors[ex], cnt);
        base_ = __shfl(base_, leader);
        if (e == ex) {
            int pos = base_ + __popcll(mask & lt);
            tok_ids[pos] = i >> 1;
            slot[i] = pos;
        }
    }
}

// ---------------- fused weight prep: all 4 transpose groups in one launch ----------------
__device__ __forceinline__ void tr_body(
    const float* __restrict__ in, u16* __restrict__ o,
    int K, int N, int n0, int k0, int radd, bool ilv)
{
    __shared__ float tile[64][65];
    const int tx = threadIdx.x & 15;
    const int ty = threadIdx.x >> 4;

    #pragma unroll
    for (int p = 0; p < 4; ++p) {
        int k = ty + p * 16;
        f32x4 v = *(const f32x4*)(in + (size_t)(k0 + k) * N + n0 + tx * 4);
        *(f32x4*)&tile[k][tx * 4] = v;
    }
    __syncthreads();
    const int kb = (threadIdx.x & 7) * 8;
    const int nr = threadIdx.x >> 3;   // 0..31
    #pragma unroll
    for (int p = 0; p < 2; ++p) {
        int n = nr + p * 32;
        u16x8 w;
        #pragma unroll
        for (int j = 0; j < 8; ++j) w[j] = f2bf(tile[kb + j][n]);
        int R = n0 + n;
        int orow = ilv ? (((R >> 4) * 32) + (R & 15) + radd) : R;
        *(u16x8*)(o + (size_t)orow * K + k0 + kb) = w;
    }
}

// grid(10560): [0,5632) WG/WU->WGUc ilv; [5632,8448) WD->WDt;
// [8448,9856) SG/SU->SGUc ilv; [9856,10560) SD->SDt
__global__ __launch_bounds__(256) void prep_w(
    const float* __restrict__ WG, const float* __restrict__ WU,
    const float* __restrict__ WD, const float* __restrict__ SG,
    const float* __restrict__ SU, const float* __restrict__ SD,
    u16* __restrict__ WGUc, u16* __restrict__ WDt,
    u16* __restrict__ SGUc, u16* __restrict__ SDt)
{
    const int zz = blockIdx.x;
    if (zz < 5632) {                        // 16 slices x (22 x 16)
        int z = zz / 352, r = zz - z * 352;
        int bx = r % 22, by = r / 22;
        const float* in = (z < 8) ? (WG + (size_t)z * HDIM * IDIM)
                                  : (WU + (size_t)(z - 8) * HDIM * IDIM);
        u16* o = WGUc + (size_t)((z < 8) ? z : z - 8) * (2 * IDIM * HDIM);
        tr_body(in, o, HDIM, IDIM, bx * 64, by * 64, (z < 8) ? 0 : 16, true);
    } else if (zz < 8448) {                 // 8 slices x (16 x 22)
        int i = zz - 5632;
        int z = i / 352, r = i - z * 352;
        int bx = r % 16, by = r / 16;
        const float* in = WD + (size_t)z * IDIM * HDIM;
        u16* o = WDt + (size_t)z * HDIM * IDIM;
        tr_body(in, o, IDIM, HDIM, bx * 64, by * 64, 0, false);
    } else if (zz < 9856) {                 // 2 slices x (44 x 16)
        int i = zz - 8448;
        int z = i / 704, r = i - z * 704;
        int bx = r % 44, by = r / 44;
        const float* in = (z == 0) ? SG : SU;
        tr_body(in, SGUc, HDIM, ISDIM, bx * 64, by * 64, (z == 0) ? 0 : 16, true);
    } else {                                // 1 slice x (16 x 44)
        int i = zz - 9856;
        int bx = i % 16, by = i / 16;
        tr_body(SD, SDt, ISDIM, HDIM, bx * 64, by * 64, 0, false);
    }
}

// ===== 256x256xBK32, 8 waves (512 thr, wave tile 128x64, acc 8x4), dbuf, 1 barrier/tile =====
// LDS: A [2 buf][256 rows][32 k] = 32KB, B same (dynamic 64KB total).
// Granule swizzle (verified 0-conflict): slot (row, s) holds granule s^((row>>1)&3).
// Staging: thread tid covers rows (tid>>2) and (tid>>2)+128 of A and B;
//   source granule ((tid&3)^((tid>>3)&3)) — valid for row+128 since 128>>1=64 == 0 mod 4.

#define BAR() __builtin_amdgcn_s_barrier()
#define WCNT0() asm volatile("s_waitcnt vmcnt(0)" ::: "memory")

#define GSTAGE(wb) do { \
    glds16(aP0, &As[(wb) + tid * 8]); \
    glds16(aP1, &As[(wb) + 4096 + tid * 8]); \
    glds16(bP0, &Bs[(wb) + tid * 8]); \
    glds16(bP1, &Bs[(wb) + 4096 + tid * 8]); \
    aP0 += 32; aP1 += 32; bP0 += 32; bP1 += 32; } while (0)

#define GEMM_TILE(rb) { \
    bf16x8 av[8], bv[4]; \
    _Pragma("unroll") for (int q = 0; q < 4; ++q) bv[q] = *(const bf16x8*)&Bs[(rb) + bofs[q]]; \
    _Pragma("unroll") for (int q = 0; q < 8; ++q) av[q] = *(const bf16x8*)&As[(rb) + aofs[q]]; \
    __builtin_amdgcn_s_setprio(1); \
    _Pragma("unroll") for (int q = 0; q < 8; ++q) \
        _Pragma("unroll") for (int w = 0; w < 4; ++w) \
            acc[q][w] = __builtin_amdgcn_mfma_f32_16x16x32_bf16(av[q], bv[w], acc[q][w], 0, 0, 0); \
    __builtin_amdgcn_s_setprio(0); }

#define GEMM_MAIN(NT) \
    GSTAGE(0); \
    _Pragma("unroll 1") \
    for (int t = 0; t < (NT) - 1; ++t) { \
        WCNT0(); BAR(); \
        GSTAGE((t & 1) ? 0 : 8192); \
        GEMM_TILE((t & 1) * 8192) \
    } \
    WCNT0(); BAR(); \
    GEMM_TILE((((NT) - 1) & 1) * 8192)

// ---------------- merged gate+up GEMM (interleaved combined weights [2N][K]) ----------------
// grid(792): zz<440 expert (widx=zz/11 m-tile of 256, nz=zz%11); zz>=440 shared (m=sidx/22, n=sidx%22)
__global__ __launch_bounds__(512, 4) void gemm_gu(
    const u16* __restrict__ A,
    const u16* __restrict__ WGUc, const u16* __restrict__ SGUc,
    u16* __restrict__ HoutE, u16* __restrict__ HoutS,
    const int* __restrict__ tok_ids, const int* __restrict__ seg_pad)
{
    extern __shared__ u16 lds[];
    u16* As = lds;
    u16* Bs = lds + 16384;

    const int zz = blockIdx.x;
    int m0, nblk, N;
    const u16* Bsrc;
    u16* Hout;
    bool gather;
    if (zz < 440) {
        int widx = zz / 11;
        nblk = zz - widx * 11;
        m0 = widx * 256;
        if (m0 >= seg_pad[NEXP]) return;
        int e = 0;
        while (e < 7 && m0 >= seg_pad[e + 1]) ++e;
        Bsrc = WGUc + (size_t)e * (2 * IDIM * HDIM);
        Hout = HoutE; N = IDIM; gather = true;
    } else {
        int sidx = zz - 440;
        int mz = sidx / 22;
        nblk = sidx - mz * 22;
        m0 = mz * 256;
        Bsrc = SGUc; Hout = HoutS; N = ISDIM; gather = false;
    }

    const int tid = threadIdx.x;
    const int srow = tid >> 2;                         // 0..127
    const int sk = (((tid & 3) ^ ((tid >> 3) & 3))) * 8;
    const int ga0 = gather ? tok_ids[m0 + srow]       : (m0 + srow);
    const int ga1 = gather ? tok_ids[m0 + 128 + srow] : (m0 + 128 + srow);
    const u16* aP0 = A + (size_t)ga0 * HDIM + sk;
    const u16* aP1 = A + (size_t)ga1 * HDIM + sk;
    const u16* bP0 = Bsrc + (size_t)(nblk * 256 + srow) * HDIM + sk;
    const u16* bP1 = Bsrc + (size_t)(nblk * 256 + 128 + srow) * HDIM + sk;

    f32x4 acc[8][4];
    #pragma unroll
    for (int i = 0; i < 8; ++i)
        #pragma unroll
        for (int j = 0; j < 4; ++j) acc[i][j] = (f32x4){0.f, 0.f, 0.f, 0.f};

    const int lane = tid & 63;
    const int wv = tid >> 6;       // 0..7
    const int wr = wv >> 2;        // 0..1  (m-half of 128)
    const int wn = wv & 3;         // 0..3  (n-quarter of 64)
    const int l15 = lane & 15;
    const int ksl = lane >> 4;
    const int kswz = ((ksl ^ ((l15 >> 1) & 3))) * 8;
    int aofs[8], bofs[4];
    #pragma unroll
    for (int q = 0; q < 8; ++q)
        aofs[q] = (wr * 128 + q * 16 + l15) * 32 + kswz;
    #pragma unroll
    for (int q = 0; q < 4; ++q)
        bofs[q] = (wn * 64 + q * 16 + l15) * 32 + kswz;

    GEMM_MAIN(32)   // K = 1024

    const int l4 = ksl * 4;
    #pragma unroll
    for (int j = 0; j < 8; ++j)
        #pragma unroll
        for (int p = 0; p < 2; ++p) {
            f32x4 g = acc[j][2 * p], u = acc[j][2 * p + 1];
            int c = nblk * 128 + (wn * 2 + p) * 16 + l15;
            #pragma unroll
            for (int jj = 0; jj < 4; ++jj) {
                int r = m0 + wr * 128 + j * 16 + l4 + jj;
                float hv = g[jj] / (1.f + __expf(-g[jj])) * u[jj];
                Hout[(size_t)r * N + c] = f2bf(hv);
            }
        }
}

// ---------------- down GEMM: grid(288) ----------------
// zz<160: expert (widx=zz>>2 m-tile of 256, n=(zz&3)*256) -> store Dexp (coalesced)
// zz>=160: shared (idx: kc=idx>>6, m=(idx&63)>>2 of 16, n=idx&3) -> atomicAdd Out (coalesced)
__global__ __launch_bounds__(512, 4) void gemm_down(
    const u16* __restrict__ AE, const u16* __restrict__ AS,
    const u16* __restrict__ WDt, const u16* __restrict__ SDt,
    float* __restrict__ DexpO, float* __restrict__ OutS,
    const int* __restrict__ seg_pad)
{
    extern __shared__ u16 lds[];
    u16* As = lds;
    u16* Bs = lds + 16384;

    const int zz = blockIdx.x;
    const bool shr = (zz >= 160);
    int m0, n0, kst;
    size_t koff;
    const u16 *Asrc, *Bsrc;
    if (!shr) {
        int widx = zz >> 2;
        n0 = (zz & 3) * 256;
        m0 = widx * 256;
        if (m0 >= seg_pad[NEXP]) return;
        int e = 0;
        while (e < 7 && m0 >= seg_pad[e + 1]) ++e;
        Asrc = AE; Bsrc = WDt + (size_t)e * (HDIM * IDIM);
        kst = IDIM; koff = 0;
    } else {
        int idx = zz - 160;        // 0..127
        int kc = idx >> 6;         // 0..1
        int rem = idx & 63;
        m0 = (rem >> 2) * 256;     // 16 m-tiles
        n0 = (rem & 3) * 256;
        Asrc = AS; Bsrc = SDt;
        kst = ISDIM; koff = (size_t)kc * 1408;
    }

    const int tid = threadIdx.x;
    const int srow = tid >> 2;
    const int sk = (((tid & 3) ^ ((tid >> 3) & 3))) * 8;
    const u16* aP0 = Asrc + (size_t)(m0 + srow) * kst + koff + sk;
    const u16* aP1 = Asrc + (size_t)(m0 + 128 + srow) * kst + koff + sk;
    const u16* bP0 = Bsrc + (size_t)(n0 + srow) * kst + koff + sk;
    const u16* bP1 = Bsrc + (size_t)(n0 + 128 + srow) * kst + koff + sk;

    f32x4 acc[8][4];
    #pragma unroll
    for (int i = 0; i < 8; ++i)
        #pragma unroll
        for (int j = 0; j < 4; ++j) acc[i][j] = (f32x4){0.f, 0.f, 0.f, 0.f};

    const int lane = tid & 63;
    const int wv = tid >> 6;
    const int wr = wv >> 2;
    const int wn = wv & 3;
    const int l15 = lane & 15;
    const int ksl = lane >> 4;
    const int kswz = ((ksl ^ ((l15 >> 1) & 3))) * 8;
    int aofs[8], bofs[4];
    #pragma unroll
    for (int q = 0; q < 8; ++q)
        aofs[q] = (wr * 128 + q * 16 + l15) * 32 + kswz;
    #pragma unroll
    for (int q = 0; q < 4; ++q)
        bofs[q] = (wn * 64 + q * 16 + l15) * 32 + kswz;

    GEMM_MAIN(44)   // K-chunk = 1408 (44 x 32) both paths

    const int l4 = ksl * 4;
    #pragma unroll
    for (int j = 0; j < 8; ++j)
        #pragma unroll
        for (int i = 0; i < 4; ++i) {
            int c = n0 + wn * 64 + i * 16 + l15;
            #pragma unroll
            for (int jj = 0; jj < 4; ++jj) {
                int r = m0 + wr * 128 + j * 16 + l4 + jj;
                if (!shr)
                    DexpO[(size_t)r * HDIM + c] = acc[j][i][jj];
                else
                    atomicAdd(&OutS[(size_t)r * HDIM + c], acc[j][i][jj]);
            }
        }
}

// ---------------- combine: out = sgate*out + w0*Dexp[s0] + w1*Dexp[s1] ----------------
__global__ __launch_bounds__(256) void combine_kernel(
    const float* __restrict__ Dexp,
    const int* __restrict__ slot, const float* __restrict__ topk_w,
    const float* __restrict__ sgate, float* __restrict__ Out)
{
    int idx = blockIdx.x * 256 + threadIdx.x;
    int t = idx >> 8;
    int c = (idx & 255) * 4;
    int s0 = slot[2 * t], s1 = slot[2 * t + 1];
    float w0 = topk_w[2 * t], w1 = topk_w[2 * t + 1], sg = sgate[t];
    f32x4 sh = *(const f32x4*)(Out + (size_t)t * HDIM + c);
    f32x4 d0 = *(const f32x4*)(Dexp + (size_t)s0 * HDIM + c);
    f32x4 d1 = *(const f32x4*)(Dexp + (size_t)s1 * HDIM + c);
    f32x4 o;
    #pragma unroll
    for (int j = 0; j < 4; ++j) o[j] = sg * sh[j] + w0 * d0[j] + w1 * d1[j];
    *(f32x4*)(Out + (size_t)t * HDIM + c) = o;
}

// ---------------- launch ----------------
extern "C" void kernel_launch(void* const* d_in, const int* in_sizes, int n_in,
                              void* d_out, int out_size, void* d_ws, size_t ws_size,
                              hipStream_t stream)
{
    const float* X   = (const float*)d_in[0];
    const float* GW  = (const float*)d_in[1];
    const float* WG  = (const float*)d_in[2];
    const float* WU  = (const float*)d_in[3];
    const float* WD  = (const float*)d_in[4];
    const float* SG  = (const float*)d_in[5];
    const float* SU  = (const float*)d_in[6];
    const float* SD  = (const float*)d_in[7];
    const float* SEG = (const float*)d_in[8];
    float* Out = (float*)d_out;

    char* ws = (char*)d_ws;
    int*   counts    = (int*)(ws + 0);
    int*   seg_pad   = (int*)(ws + 64);
    int*   cursors   = (int*)(ws + 128);
    int*   topk_e    = (int*)(ws + 1024);
    float* topk_w    = (float*)(ws + 1024 + 32768);
    float* sgate     = (float*)(ws + 1024 + 65536);
    int*   slot      = (int*)(ws + 1024 + 65536 + 16384);
    int*   tok_ids   = (int*)(ws + 1024 + 65536 + 16384 + 32768);   // 10240 ints

    u16* Xbf  = (u16*)(ws + 0x0040000ull);   // 8.39 MB
    u16* Hact = (u16*)(ws + 0x0840000ull);   // 10240x1408 bf16 = 28.8 MB
    u16* Hs   = (u16*)(ws + 0x23C0000ull);   // 4096x2816 bf16 = 23.1 MB
    u16* WGUc = (u16*)(ws + 0x39C0000ull);   // 8 x ilv [2816][1024] = 46.1 MB
    u16* WDt  = (u16*)(ws + 0x65C0000ull);   // 8 x [1024][1408] = 23.1 MB
    u16* SGUc = (u16*)(ws + 0x7BC0000ull);   // ilv [5632][1024] = 11.5 MB
    u16* SDt  = (u16*)(ws + 0x86C0000ull);   // [1024][2816] = 5.8 MB
    // Dexp (10240x1024 f32 = 41.9 MB) aliases WGUc (46.1 MB), written after gemm_gu
    float* Dexp = (float*)(ws + 0x39C0000ull);

    hipMemsetAsync(counts, 0, 64, stream);
    hipMemsetAsync(Out, 0, (size_t)T_TOK * HDIM * sizeof(float), stream);

    // routing (+ fused X->bf16 convert)
    route_kernel<<<T_TOK / 4, 256, 0, stream>>>(X, GW, SEG, topk_e, topk_w, sgate, Xbf);
    hist_kernel<<<(T_TOK * 2) / 256, 256, 0, stream>>>(topk_e, counts, tok_ids);
    offsets_kernel<<<1, 64, 0, stream>>>(counts, seg_pad, cursors);
    scatter_kernel<<<(T_TOK * 2) / 256, 256, 0, stream>>>(topk_e, cursors, tok_ids, slot);

    // fused weight prep (all transposes, one launch)
    prep_w<<<10560, 256, 0, stream>>>(WG, WU, WD, SG, SU, SD, WGUc, WDt, SGUc, SDt);

    // merged gate+up: expert (40 padded m-tiles x 11 n) + shared (16 x 22)
    gemm_gu<<<792, 512, 65536, stream>>>(
        Xbf, WGUc, SGUc, Hact, Hs, tok_ids, seg_pad);

    // merged down: expert (40 x 4) -> Dexp, shared (2 kc x 16 x 4) -> atomicAdd Out
    gemm_down<<<288, 512, 65536, stream>>>(
        Hact, Hs, WDt, SDt, Dexp, Out, seg_pad);

    // final combine
    combine_kernel<<<(T_TOK * HDIM / 4) / 256, 256, 0, stream>>>(
        Dexp, slot, topk_w, sgate, Out);
}

// Round 21
// 295.868 us; speedup vs baseline: 6.9358x; 6.9358x over previous
//
#include <hip/hip_runtime.h>
#include <hip/hip_bf16.h>

#define T_TOK 4096
#define HDIM  1024
#define NEXP  8
#define IDIM  1408
#define ISDIM 2816
#define PADT  10240   // 40 tiles of 256 (worst-case padded expert rows)

typedef short bf16x8 __attribute__((ext_vector_type(8)));
typedef float f32x4  __attribute__((ext_vector_type(4)));
typedef unsigned short u16;
typedef unsigned short u16x4 __attribute__((ext_vector_type(4)));
typedef unsigned short u16x8 __attribute__((ext_vector_type(8)));

typedef __attribute__((address_space(1))) const void gvoid;
typedef __attribute__((address_space(3))) void lvoid;

__device__ __forceinline__ u16 f2bf(float f) {
    union { float f; unsigned u; } c; c.f = f;
    unsigned r = (c.u + 0x7FFFu + ((c.u >> 16) & 1u)) >> 16;
    return (u16)r;
}
__device__ __forceinline__ float bf2f(u16 v) {
    union { unsigned u; float f; } c; c.u = (unsigned)v << 16; return c.f;
}
__device__ __forceinline__ void glds16(const u16* g, u16* l) {
    __builtin_amdgcn_global_load_lds((gvoid*)g, (lvoid*)l, 16, 0, 0);
}

// ---------------- routing: one wave per token (no atomics) + fused X->bf16 ----------------
__global__ __launch_bounds__(256) void route_kernel(
    const float* __restrict__ X, const float* __restrict__ GW,
    const float* __restrict__ SEG,
    int* __restrict__ topk_e, float* __restrict__ topk_w,
    float* __restrict__ sgate, u16* __restrict__ Xbf)
{
    const int t = blockIdx.x * 4 + (threadIdx.x >> 6);
    const int lane = threadIdx.x & 63;
    float acc[NEXP];
    #pragma unroll
    for (int e = 0; e < NEXP; ++e) acc[e] = 0.f;
    float sacc = 0.f;
    const float* xr = X + (size_t)t * HDIM;
    u16* xw = Xbf + (size_t)t * HDIM;
    for (int h = lane; h < HDIM; h += 64) {
        float xv = xr[h];
        xw[h] = f2bf(xv);
        f32x4 g0 = *(const f32x4*)(GW + (size_t)h * NEXP);
        f32x4 g1 = *(const f32x4*)(GW + (size_t)h * NEXP + 4);
        acc[0] += xv * g0[0]; acc[1] += xv * g0[1];
        acc[2] += xv * g0[2]; acc[3] += xv * g0[3];
        acc[4] += xv * g1[0]; acc[5] += xv * g1[1];
        acc[6] += xv * g1[2]; acc[7] += xv * g1[3];
        sacc += xv * SEG[h];
    }
    #pragma unroll
    for (int off = 32; off > 0; off >>= 1) {
        #pragma unroll
        for (int e = 0; e < NEXP; ++e) acc[e] += __shfl_down(acc[e], off);
        sacc += __shfl_down(sacc, off);
    }
    if (lane == 0) {
        int e0 = 0;
        #pragma unroll
        for (int e = 1; e < NEXP; ++e) if (acc[e] > acc[e0]) e0 = e;
        int e1 = (e0 == 0) ? 1 : 0;
        #pragma unroll
        for (int e = 0; e < NEXP; ++e)
            if (e != e0 && acc[e] > acc[e1]) e1 = e;
        float w0 = 1.f / (1.f + __expf(acc[e1] - acc[e0]));
        topk_e[t * 2]     = e0; topk_e[t * 2 + 1] = e1;
        topk_w[t * 2]     = w0; topk_w[t * 2 + 1] = 1.f - w0;
        sgate[t] = 1.f / (1.f + __expf(-sacc));
    }
}

// ---------------- histogram (+ tok_ids prefill) ----------------
__global__ __launch_bounds__(256) void hist_kernel(
    const int* __restrict__ topk_e, int* __restrict__ counts,
    int* __restrict__ tok_ids)
{
    __shared__ int h[NEXP];
    if (threadIdx.x < NEXP) h[threadIdx.x] = 0;
    __syncthreads();
    int i = blockIdx.x * 256 + threadIdx.x;
    atomicAdd(&h[topk_e[i]], 1);
    for (int j = i; j < PADT; j += gridDim.x * 256) tok_ids[j] = 0;
    __syncthreads();
    if (threadIdx.x < NEXP) atomicAdd(&counts[threadIdx.x], h[threadIdx.x]);
}

// seg_pad[e]: 256-aligned padded segment starts; seg_pad[8] = padded total
__global__ void offsets_kernel(const int* __restrict__ counts,
                               int* __restrict__ seg_pad,
                               int* __restrict__ cursors)
{
    if (threadIdx.x == 0) {
        int s = 0;
        for (int e = 0; e < NEXP; ++e) {
            seg_pad[e] = s; cursors[e] = s;
            s += ((counts[e] + 255) >> 8) << 8;
        }
        seg_pad[NEXP] = s;
    }
}

// ---------------- scatter (writes tok_ids + slot inverse map) ----------------
__global__ __launch_bounds__(256) void scatter_kernel(
    const int* __restrict__ topk_e,
    int* __restrict__ cursors, int* __restrict__ tok_ids,
    int* __restrict__ slot)
{
    const int i = blockIdx.x * 256 + threadIdx.x;
    const int lane = threadIdx.x & 63;
    const int e = topk_e[i];
    const unsigned long long lt = (1ull << lane) - 1ull;
    #pragma unroll
    for (int ex = 0; ex < NEXP; ++ex) {
        unsigned long long mask = __ballot(e == ex);
        if (mask == 0ull) continue;
        int cnt = __popcll(mask);
        int leader = __ffsll((long long)mask) - 1;
        int base_ = 0;
        if (lane == leader) base_ = atomicAdd(&cursors[ex], cnt);
        base_ = __shfl(base_, leader);
        if (e == ex) {
            int pos = base_ + __popcll(mask & lt);
            tok_ids[pos] = i >> 1;
            slot[i] = pos;
        }
    }
}

// ---------------- fused weight prep: all 4 transpose groups in one launch ----------------
__device__ __forceinline__ void tr_body(
    const float* __restrict__ in, u16* __restrict__ o,
    int K, int N, int n0, int k0, int radd, bool ilv)
{
    __shared__ float tile[64][65];
    const int tx = threadIdx.x & 15;
    const int ty = threadIdx.x >> 4;

    #pragma unroll
    for (int p = 0; p < 4; ++p) {
        int k = ty + p * 16;
        f32x4 v = *(const f32x4*)(in + (size_t)(k0 + k) * N + n0 + tx * 4);
        *(f32x4*)&tile[k][tx * 4] = v;
    }
    __syncthreads();
    const int kb = (threadIdx.x & 7) * 8;
    const int nr = threadIdx.x >> 3;   // 0..31
    #pragma unroll
    for (int p = 0; p < 2; ++p) {
        int n = nr + p * 32;
        u16x8 w;
        #pragma unroll
        for (int j = 0; j < 8; ++j) w[j] = f2bf(tile[kb + j][n]);
        int R = n0 + n;
        int orow = ilv ? (((R >> 4) * 32) + (R & 15) + radd) : R;
        *(u16x8*)(o + (size_t)orow * K + k0 + kb) = w;
    }
}

// grid(10560): [0,5632) WG/WU->WGUc ilv; [5632,8448) WD->WDt;
// [8448,9856) SG/SU->SGUc ilv; [9856,10560) SD->SDt
__global__ __launch_bounds__(256) void prep_w(
    const float* __restrict__ WG, const float* __restrict__ WU,
    const float* __restrict__ WD, const float* __restrict__ SG,
    const float* __restrict__ SU, const float* __restrict__ SD,
    u16* __restrict__ WGUc, u16* __restrict__ WDt,
    u16* __restrict__ SGUc, u16* __restrict__ SDt)
{
    const int zz = blockIdx.x;
    if (zz < 5632) {                        // 16 slices x (22 x 16)
        int z = zz / 352, r = zz - z * 352;
        int bx = r % 22, by = r / 22;
        const float* in = (z < 8) ? (WG + (size_t)z * HDIM * IDIM)
                                  : (WU + (size_t)(z - 8) * HDIM * IDIM);
        u16* o = WGUc + (size_t)((z < 8) ? z : z - 8) * (2 * IDIM * HDIM);
        tr_body(in, o, HDIM, IDIM, bx * 64, by * 64, (z < 8) ? 0 : 16, true);
    } else if (zz < 8448) {                 // 8 slices x (16 x 22)
        int i = zz - 5632;
        int z = i / 352, r = i - z * 352;
        int bx = r % 16, by = r / 16;
        const float* in = WD + (size_t)z * IDIM * HDIM;
        u16* o = WDt + (size_t)z * HDIM * IDIM;
        tr_body(in, o, IDIM, HDIM, bx * 64, by * 64, 0, false);
    } else if (zz < 9856) {                 // 2 slices x (44 x 16)
        int i = zz - 8448;
        int z = i / 704, r = i - z * 704;
        int bx = r % 44, by = r / 44;
        const float* in = (z == 0) ? SG : SU;
        tr_body(in, SGUc, HDIM, ISDIM, bx * 64, by * 64, (z == 0) ? 0 : 16, true);
    } else {                                // 1 slice x (16 x 44)
        int i = zz - 9856;
        int bx = i % 16, by = i / 16;
        tr_body(SD, SDt, ISDIM, HDIM, bx * 64, by * 64, 0, false);
    }
}

// ===== 256x256xBK32, 16 waves (1024 thr, wave tile 64x64), dbuf, 1 barrier/tile =====
// LDS: A [2 buf][256 rows][32 k] = 32KB, B same (dynamic 64KB total).
// Granule swizzle (verified 0-conflict): slot (row, s) holds granule s^((row>>1)&3).

#define BAR() __builtin_amdgcn_s_barrier()
#define WCNT0() asm volatile("s_waitcnt vmcnt(0)" ::: "memory")

#define GSTAGE(wb) do { \
    glds16(aP, &As[(wb) + tid * 8]); \
    glds16(bP, &Bs[(wb) + tid * 8]); \
    aP += 32; bP += 32; } while (0)

#define GEMM_TILE(rb) { \
    bf16x8 av[4], bv[4]; \
    _Pragma("unroll") for (int q = 0; q < 4; ++q) bv[q] = *(const bf16x8*)&Bs[(rb) + bofs[q]]; \
    _Pragma("unroll") for (int q = 0; q < 4; ++q) av[q] = *(const bf16x8*)&As[(rb) + aofs[q]]; \
    __builtin_amdgcn_s_setprio(1); \
    _Pragma("unroll") for (int q = 0; q < 4; ++q) \
        _Pragma("unroll") for (int w = 0; w < 4; ++w) \
            acc[q][w] = __builtin_amdgcn_mfma_f32_16x16x32_bf16(av[q], bv[w], acc[q][w], 0, 0, 0); \
    __builtin_amdgcn_s_setprio(0); }

#define GEMM_MAIN(NT) \
    GSTAGE(0); \
    _Pragma("unroll 1") \
    for (int t = 0; t < (NT) - 1; ++t) { \
        WCNT0(); BAR(); \
        GSTAGE((t & 1) ? 0 : 8192); \
        GEMM_TILE((t & 1) * 8192) \
    } \
    WCNT0(); BAR(); \
    GEMM_TILE((((NT) - 1) & 1) * 8192)

// ---------------- merged gate+up GEMM (interleaved combined weights [2N][K]) ----------------
// grid(792): zz<440 expert (widx=zz/11 m-tile of 256, nz=zz%11); zz>=440 shared (m=sidx/22, n=sidx%22)
__global__ __launch_bounds__(1024, 4) void gemm_gu(
    const u16* __restrict__ A,
    const u16* __restrict__ WGUc, const u16* __restrict__ SGUc,
    u16* __restrict__ HoutE, u16* __restrict__ HoutS,
    const int* __restrict__ tok_ids, const int* __restrict__ seg_pad)
{
    extern __shared__ u16 lds[];
    u16* As = lds;
    u16* Bs = lds + 16384;

    const int zz = blockIdx.x;
    int m0, nblk, N;
    const u16* Bsrc;
    u16* Hout;
    bool gather;
    if (zz < 440) {
        int widx = zz / 11;
        nblk = zz - widx * 11;
        m0 = widx * 256;
        if (m0 >= seg_pad[NEXP]) return;
        int e = 0;
        while (e < 7 && m0 >= seg_pad[e + 1]) ++e;
        Bsrc = WGUc + (size_t)e * (2 * IDIM * HDIM);
        Hout = HoutE; N = IDIM; gather = true;
    } else {
        int sidx = zz - 440;
        int mz = sidx / 22;
        nblk = sidx - mz * 22;
        m0 = mz * 256;
        Bsrc = SGUc; Hout = HoutS; N = ISDIM; gather = false;
    }

    const int tid = threadIdx.x;
    const int srow = tid >> 2;
    const int sk = (((tid & 3) ^ ((tid >> 3) & 3))) * 8;
    const int arow = m0 + srow;
    const int ga = gather ? tok_ids[arow] : arow;
    const u16* aP = A + (size_t)ga * HDIM + sk;
    const u16* bP = Bsrc + (size_t)(nblk * 256 + srow) * HDIM + sk;

    f32x4 acc[4][4];
    #pragma unroll
    for (int i = 0; i < 4; ++i)
        #pragma unroll
        for (int j = 0; j < 4; ++j) acc[i][j] = (f32x4){0.f, 0.f, 0.f, 0.f};

    const int lane = tid & 63;
    const int wv = tid >> 6;
    const int wr = wv >> 2;
    const int wn = wv & 3;
    const int l15 = lane & 15;
    const int ksl = lane >> 4;
    const int kswz = ((ksl ^ ((l15 >> 1) & 3))) * 8;
    int aofs[4], bofs[4];
    #pragma unroll
    for (int q = 0; q < 4; ++q) {
        aofs[q] = (wr * 64 + q * 16 + l15) * 32 + kswz;
        bofs[q] = (wn * 64 + q * 16 + l15) * 32 + kswz;
    }

    GEMM_MAIN(32)   // K = 1024

    const int l4 = ksl * 4;
    #pragma unroll
    for (int j = 0; j < 4; ++j)
        #pragma unroll
        for (int p = 0; p < 2; ++p) {
            f32x4 g = acc[j][2 * p], u = acc[j][2 * p + 1];
            int c = nblk * 128 + (wn * 2 + p) * 16 + l15;
            #pragma unroll
            for (int jj = 0; jj < 4; ++jj) {
                int r = m0 + wr * 64 + j * 16 + l4 + jj;
                float hv = g[jj] / (1.f + __expf(-g[jj])) * u[jj];
                Hout[(size_t)r * N + c] = f2bf(hv);
            }
        }
}

// ---------------- down GEMM: grid(288) ----------------
// zz<160: expert (widx=zz>>2 m-tile of 256, n=(zz&3)*256) -> store Dexp (coalesced)
// zz>=160: shared (idx: kc=idx>>6, m=(idx&63)>>2 of 16, n=idx&3) -> atomicAdd Out (coalesced)
__global__ __launch_bounds__(1024, 4) void gemm_down(
    const u16* __restrict__ AE, const u16* __restrict__ AS,
    const u16* __restrict__ WDt, const u16* __restrict__ SDt,
    float* __restrict__ DexpO, float* __restrict__ OutS,
    const int* __restrict__ seg_pad)
{
    extern __shared__ u16 lds[];
    u16* As = lds;
    u16* Bs = lds + 16384;

    const int zz = blockIdx.x;
    const bool shr = (zz >= 160);
    int m0, n0, kst;
    size_t koff;
    const u16 *Asrc, *Bsrc;
    if (!shr) {
        int widx = zz >> 2;
        n0 = (zz & 3) * 256;
        m0 = widx * 256;
        if (m0 >= seg_pad[NEXP]) return;
        int e = 0;
        while (e < 7 && m0 >= seg_pad[e + 1]) ++e;
        Asrc = AE; Bsrc = WDt + (size_t)e * (HDIM * IDIM);
        kst = IDIM; koff = 0;
    } else {
        int idx = zz - 160;        // 0..127
        int kc = idx >> 6;         // 0..1
        int rem = idx & 63;
        m0 = (rem >> 2) * 256;     // 16 m-tiles
        n0 = (rem & 3) * 256;
        Asrc = AS; Bsrc = SDt;
        kst = ISDIM; koff = (size_t)kc * 1408;
    }

    const int tid = threadIdx.x;
    const int srow = tid >> 2;
    const int sk = (((tid & 3) ^ ((tid >> 3) & 3))) * 8;
    const u16* aP = Asrc + (size_t)(m0 + srow) * kst + koff + sk;
    const u16* bP = Bsrc + (size_t)(n0 + srow) * kst + koff + sk;

    f32x4 acc[4][4];
    #pragma unroll
    for (int i = 0; i < 4; ++i)
        #pragma unroll
        for (int j = 0; j < 4; ++j) acc[i][j] = (f32x4){0.f, 0.f, 0.f, 0.f};

    const int lane = tid & 63;
    const int wv = tid >> 6;
    const int wr = wv >> 2;
    const int wn = wv & 3;
    const int l15 = lane & 15;
    const int ksl = lane >> 4;
    const int kswz = ((ksl ^ ((l15 >> 1) & 3))) * 8;
    int aofs[4], bofs[4];
    #pragma unroll
    for (int q = 0; q < 4; ++q) {
        aofs[q] = (wr * 64 + q * 16 + l15) * 32 + kswz;
        bofs[q] = (wn * 64 + q * 16 + l15) * 32 + kswz;
    }

    GEMM_MAIN(44)   // K-chunk = 1408 (44 x 32) both paths

    const int l4 = ksl * 4;
    #pragma unroll
    for (int j = 0; j < 4; ++j)
        #pragma unroll
        for (int i = 0; i < 4; ++i) {
            int c = n0 + wn * 64 + i * 16 + l15;
            #pragma unroll
            for (int jj = 0; jj < 4; ++jj) {
                int r = m0 + wr * 64 + j * 16 + l4 + jj;
                if (!shr)
                    DexpO[(size_t)r * HDIM + c] = acc[j][i][jj];
                else
                    atomicAdd(&OutS[(size_t)r * HDIM + c], acc[j][i][jj]);
            }
        }
}

// ---------------- combine: out = sgate*out + w0*Dexp[s0] + w1*Dexp[s1] ----------------
__global__ __launch_bounds__(256) void combine_kernel(
    const float* __restrict__ Dexp,
    const int* __restrict__ slot, const float* __restrict__ topk_w,
    const float* __restrict__ sgate, float* __restrict__ Out)
{
    int idx = blockIdx.x * 256 + threadIdx.x;
    int t = idx >> 8;
    int c = (idx & 255) * 4;
    int s0 = slot[2 * t], s1 = slot[2 * t + 1];
    float w0 = topk_w[2 * t], w1 = topk_w[2 * t + 1], sg = sgate[t];
    f32x4 sh = *(const f32x4*)(Out + (size_t)t * HDIM + c);
    f32x4 d0 = *(const f32x4*)(Dexp + (size_t)s0 * HDIM + c);
    f32x4 d1 = *(const f32x4*)(Dexp + (size_t)s1 * HDIM + c);
    f32x4 o;
    #pragma unroll
    for (int j = 0; j < 4; ++j) o[j] = sg * sh[j] + w0 * d0[j] + w1 * d1[j];
    *(f32x4*)(Out + (size_t)t * HDIM + c) = o;
}

// ---------------- launch ----------------
extern "C" void kernel_launch(void* const* d_in, const int* in_sizes, int n_in,
                              void* d_out, int out_size, void* d_ws, size_t ws_size,
                              hipStream_t stream)
{
    const float* X   = (const float*)d_in[0];
    const float* GW  = (const float*)d_in[1];
    const float* WG  = (const float*)d_in[2];
    const float* WU  = (const float*)d_in[3];
    const float* WD  = (const float*)d_in[4];
    const float* SG  = (const float*)d_in[5];
    const float* SU  = (const float*)d_in[6];
    const float* SD  = (const float*)d_in[7];
    const float* SEG = (const float*)d_in[8];
    float* Out = (float*)d_out;

    char* ws = (char*)d_ws;
    int*   counts    = (int*)(ws + 0);
    int*   seg_pad   = (int*)(ws + 64);
    int*   cursors   = (int*)(ws + 128);
    int*   topk_e    = (int*)(ws + 1024);
    float* topk_w    = (float*)(ws + 1024 + 32768);
    float* sgate     = (float*)(ws + 1024 + 65536);
    int*   slot      = (int*)(ws + 1024 + 65536 + 16384);
    int*   tok_ids   = (int*)(ws + 1024 + 65536 + 16384 + 32768);   // 10240 ints

    u16* Xbf  = (u16*)(ws + 0x0040000ull);   // 8.39 MB
    u16* Hact = (u16*)(ws + 0x0840000ull);   // 10240x1408 bf16 = 28.8 MB
    u16* Hs   = (u16*)(ws + 0x23C0000ull);   // 4096x2816 bf16 = 23.1 MB
    u16* WGUc = (u16*)(ws + 0x39C0000ull);   // 8 x ilv [2816][1024] = 46.1 MB
    u16* WDt  = (u16*)(ws + 0x65C0000ull);   // 8 x [1024][1408] = 23.1 MB
    u16* SGUc = (u16*)(ws + 0x7BC0000ull);   // ilv [5632][1024] = 11.5 MB
    u16* SDt  = (u16*)(ws + 0x86C0000ull);   // [1024][2816] = 5.8 MB
    // Dexp (10240x1024 f32 = 41.9 MB) aliases WGUc (46.1 MB), written after gemm_gu
    float* Dexp = (float*)(ws + 0x39C0000ull);

    hipMemsetAsync(counts, 0, 64, stream);
    hipMemsetAsync(Out, 0, (size_t)T_TOK * HDIM * sizeof(float), stream);

    // routing (+ fused X->bf16 convert)
    route_kernel<<<T_TOK / 4, 256, 0, stream>>>(X, GW, SEG, topk_e, topk_w, sgate, Xbf);
    hist_kernel<<<(T_TOK * 2) / 256, 256, 0, stream>>>(topk_e, counts, tok_ids);
    offsets_kernel<<<1, 64, 0, stream>>>(counts, seg_pad, cursors);
    scatter_kernel<<<(T_TOK * 2) / 256, 256, 0, stream>>>(topk_e, cursors, tok_ids, slot);

    // fused weight prep (all transposes, one launch)
    prep_w<<<10560, 256, 0, stream>>>(WG, WU, WD, SG, SU, SD, WGUc, WDt, SGUc, SDt);

    // merged gate+up: expert (40 padded m-tiles x 11 n) + shared (16 x 22)
    gemm_gu<<<792, 1024, 65536, stream>>>(
        Xbf, WGUc, SGUc, Hact, Hs, tok_ids, seg_pad);

    // merged down: expert (40 x 4) -> Dexp, shared (2 kc x 16 x 4) -> atomicAdd Out
    gemm_down<<<288, 1024, 65536, stream>>>(
        Hact, Hs, WDt, SDt, Dexp, Out, seg_pad);

    // final combine
    combine_kernel<<<(T_TOK * HDIM / 4) / 256, 256, 0, stream>>>(
        Dexp, slot, topk_w, sgate, Out);
}